// Round 8
// baseline (640.623 us; speedup 1.0000x reference)
//
#include <hip/hip_runtime.h>
#include <hip/hip_bf16.h>

// Problem constants (B=1)
#define CL 2048   // sequence length
#define CD 1024   // hidden
#define CH 16     // heads
#define CHD 64    // head dim
#define NEGS -1e30f

typedef __attribute__((ext_vector_type(8))) short short8;  // 8 x bf16 frag
typedef __attribute__((ext_vector_type(4))) float f32x4;
// Register row for Michelot. Lifetime = phase 2 ONLY, all indices static
// (loaded via one unrolled 8x ds_read_b128 loop) -> stays in arch VGPRs.
typedef __attribute__((ext_vector_type(32))) float f32x32;

__device__ __forceinline__ float wave_sum(float x) {
#pragma unroll
  for (int m = 32; m >= 1; m >>= 1) x += __shfl_xor(x, m, 64);
  return x;
}
__device__ __forceinline__ float wave_max(float x) {
#pragma unroll
  for (int m = 32; m >= 1; m >>= 1) x = fmaxf(x, __shfl_xor(x, m, 64));
  return x;
}

__device__ __forceinline__ void split1(float v, short& h, short& l) {
  __hip_bfloat16 bh = __float2bfloat16(v);
  __hip_bfloat16 bl = __float2bfloat16(v - __bfloat162float(bh));
  h = __builtin_bit_cast(short, bh);
  l = __builtin_bit_cast(short, bl);
}
__device__ __forceinline__ unsigned short bf16_bits(float v) {
  __hip_bfloat16 b = __float2bfloat16(v);
  return (unsigned short)__builtin_bit_cast(short, b);
}

// ---- depth-5 tree helpers over f32x32 ----
__device__ __forceinline__ float tree_sum_valid(const f32x32& s) {
  float t[8];
#pragma unroll
  for (int i = 0; i < 8; i++) {
    const float a = s[i]      > -1e29f ? s[i]      : 0.f;
    const float b = s[i + 8]  > -1e29f ? s[i + 8]  : 0.f;
    const float c = s[i + 16] > -1e29f ? s[i + 16] : 0.f;
    const float d = s[i + 24] > -1e29f ? s[i + 24] : 0.f;
    t[i] = (a + b) + (c + d);
  }
#pragma unroll
  for (int i = 0; i < 4; i++) t[i] += t[i + 4];
  t[0] += t[2]; t[1] += t[3];
  return t[0] + t[1];
}
__device__ __forceinline__ float tree_max(const f32x32& s) {
  float t[8];
#pragma unroll
  for (int i = 0; i < 8; i++)
    t[i] = fmaxf(fmaxf(s[i], s[i + 8]), fmaxf(s[i + 16], s[i + 24]));
#pragma unroll
  for (int i = 0; i < 4; i++) t[i] = fmaxf(t[i], t[i + 4]);
  return fmaxf(fmaxf(t[0], t[2]), fmaxf(t[1], t[3]));
}
__device__ __forceinline__ void masked_sc(const f32x32& s, float tau,
                                          float& cs, float& cn) {
  float ts[8], tc[8];
#pragma unroll
  for (int i = 0; i < 8; i++) {
    const float a = s[i], b = s[i + 8], c = s[i + 16], d = s[i + 24];
    ts[i] = ((a > tau ? a : 0.f) + (b > tau ? b : 0.f)) +
            ((c > tau ? c : 0.f) + (d > tau ? d : 0.f));
    tc[i] = ((a > tau ? 1.f : 0.f) + (b > tau ? 1.f : 0.f)) +
            ((c > tau ? 1.f : 0.f) + (d > tau ? 1.f : 0.f));
  }
#pragma unroll
  for (int i = 0; i < 4; i++) { ts[i] += ts[i + 4]; tc[i] += tc[i + 4]; }
  ts[0] += ts[2]; ts[1] += ts[3]; tc[0] += tc[2]; tc[1] += tc[3];
  cs = ts[0] + ts[1];
  cn = tc[0] + tc[1];
}
__device__ __forceinline__ float relu_store_sum(f32x32& s, float ts_) {
  float t[8];
#pragma unroll
  for (int i = 0; i < 8; i++) {
    float a = s[i] - ts_;      a = a > 0.f ? a : 0.f;
    float b = s[i + 8] - ts_;  b = b > 0.f ? b : 0.f;
    float c = s[i + 16] - ts_; c = c > 0.f ? c : 0.f;
    float d = s[i + 24] - ts_; d = d > 0.f ? d : 0.f;
    s[i] = a; s[i + 8] = b; s[i + 16] = c; s[i + 24] = d;
    t[i] = (a + b) + (c + d);
  }
#pragma unroll
  for (int i = 0; i < 4; i++) t[i] += t[i + 4];
  t[0] += t[2]; t[1] += t[3];
  return t[0] + t[1];
}

// Fused 2-row warm-start Michelot (verified passing in round 7, absmax 3.9e-3).
// tau* in [max-1, max-1/n] => {s > max-1.000001} is a superset of the support;
// fixpoint count == reference's sort-based k_support. Reference quirk kept:
// tau_star = (FULL masked row sum - 1)/cnt. Overwrites s with unnormalized p.
__device__ __forceinline__ void entmax2(f32x32& sa, f32x32& sb,
                                        float& inva, float& invb) {
  const float ssa = wave_sum(tree_sum_valid(sa));
  const float ssb = wave_sum(tree_sum_valid(sb));
  const float ma = wave_max(tree_max(sa));
  const float mb = wave_max(tree_max(sb));
  float taua = ma - 1.000001f, taub = mb - 1.000001f;
  int cnta = 0, cntb = 0;
  bool runa = true, runb = true;
  for (int it = 0; it < 64; it++) {
    float csa, cna, csb, cnb;
    masked_sc(sa, taua, csa, cna);
    masked_sc(sb, taub, csb, cnb);
    csa = wave_sum(csa); cna = wave_sum(cna);
    csb = wave_sum(csb); cnb = wave_sum(cnb);
    if (runa) {
      const int nc = (int)cna;
      if (nc == cnta) runa = false;
      else { cnta = nc; taua = (csa - 1.f) / cna; }
    }
    if (runb) {
      const int nc = (int)cnb;
      if (nc == cntb) runb = false;
      else { cntb = nc; taub = (csb - 1.f) / cnb; }
    }
    if (!runa && !runb) break;  // wave-uniform
  }
  const float tsa = (ssa - 1.f) / (float)cnta;
  const float tsb = (ssb - 1.f) / (float)cntb;
  inva = 1.f / (wave_sum(relu_store_sum(sa, tsa)) + 1e-10f);
  invb = 1.f / (wave_sum(relu_store_sum(sb, tsb)) + 1e-10f);
}

// One fused split kernel: fp32 -> bf16 hi/lo planes for x and 4 weights.
__global__ __launch_bounds__(256) void split_all(
    const float* __restrict__ x,  const float* __restrict__ wq,
    const float* __restrict__ wk, const float* __restrict__ wv,
    const float* __restrict__ wo,
    short* __restrict__ xh,  short* __restrict__ xl,
    short* __restrict__ wqh, short* __restrict__ wql,
    short* __restrict__ wkh, short* __restrict__ wkl,
    short* __restrict__ wvh, short* __restrict__ wvl,
    short* __restrict__ woh, short* __restrict__ wol) {
  const int b = blockIdx.x;
  const float* src; short *dh, *dl; int i0;
  if      (b < 2048) { src = x;  dh = xh;  dl = xl;  i0 = b; }
  else if (b < 3072) { src = wq; dh = wqh; dl = wql; i0 = b - 2048; }
  else if (b < 4096) { src = wk; dh = wkh; dl = wkl; i0 = b - 3072; }
  else if (b < 5120) { src = wv; dh = wvh; dl = wvl; i0 = b - 4096; }
  else               { src = wo; dh = woh; dl = wol; i0 = b - 5120; }
  const int i = i0 * 256 + threadIdx.x;
  const float4 v = reinterpret_cast<const float4*>(src)[i];
  const float vv[4] = {v.x, v.y, v.z, v.w};
  short hh[4], ll[4];
#pragma unroll
  for (int e = 0; e < 4; e++) split1(vv[e], hh[e], ll[e]);
  reinterpret_cast<short4*>(dh)[i] = make_short4(hh[0], hh[1], hh[2], hh[3]);
  reinterpret_cast<short4*>(dl)[i] = make_short4(ll[0], ll[1], ll[2], ll[3]);
}

// C[2048,1024] = (Ah+Al) * (B?h+B?l)^T via 3-term split-bf16 MFMA.
// 128x128 tile/WG, LDS-staged BK=32. Epilogue: fp32out -> Cf; else bf16 hi/lo
// planes (sel 2 = vT transposed [dim][seq] for the P@V B-operand).
__global__ __launch_bounds__(256, 2) void gemm128_split(
    const short* __restrict__ Ah, const short* __restrict__ Al,
    const short* __restrict__ B0h, const short* __restrict__ B0l,
    const short* __restrict__ B1h, const short* __restrict__ B1l,
    const short* __restrict__ B2h, const short* __restrict__ B2l,
    short* __restrict__ O0h, short* __restrict__ O0l,
    short* __restrict__ O1h, short* __restrict__ O1l,
    short* __restrict__ O2h, short* __restrict__ O2l,
    float* __restrict__ Cf, int fp32out) {
  __shared__ short AhS[128][32], AlS[128][32], BhS[128][32], BlS[128][32];
  const int tid = threadIdx.x, lane = tid & 63, wave = tid >> 6;
  const int l15 = lane & 15, quad = lane >> 4;
  const int sel = blockIdx.x >> 3, nb = blockIdx.x & 7;
  const short* Bh = sel == 0 ? B0h : (sel == 1 ? B1h : B2h);
  const short* Bl = sel == 0 ? B0l : (sel == 1 ? B1l : B2l);
  const int m0 = blockIdx.y * 128, n0 = nb * 128;
  const int wm = (wave >> 1) * 64, wn = (wave & 1) * 64;

  f32x4 acc[4][4];
#pragma unroll
  for (int i = 0; i < 4; i++)
#pragma unroll
    for (int j = 0; j < 4; j++) acc[i][j] = {0.f, 0.f, 0.f, 0.f};

  const short* gsrc = wave == 0 ? Ah : wave == 1 ? Al : wave == 2 ? Bh : Bl;
  short(*ldst)[32] = wave == 0 ? AhS : wave == 1 ? AlS : wave == 2 ? BhS : BlS;
  const int srow0 = (wave < 2) ? m0 : n0;

  for (int k0 = 0; k0 < CD; k0 += 32) {
#pragma unroll
    for (int i = 0; i < 8; i++) {
      const int ci = i * 64 + lane;
      const int r = ci >> 2, kc = (ci & 3) * 8;
      *reinterpret_cast<short8*>(&ldst[r][kc]) =
          *reinterpret_cast<const short8*>(&gsrc[(size_t)(srow0 + r) * CD + k0 + kc]);
    }
    __syncthreads();
    short8 a_h[4], a_l[4], b_h[4], b_l[4];
#pragma unroll
    for (int i = 0; i < 4; i++) {
      a_h[i] = *reinterpret_cast<const short8*>(&AhS[wm + i * 16 + l15][quad * 8]);
      a_l[i] = *reinterpret_cast<const short8*>(&AlS[wm + i * 16 + l15][quad * 8]);
      b_h[i] = *reinterpret_cast<const short8*>(&BhS[wn + i * 16 + l15][quad * 8]);
      b_l[i] = *reinterpret_cast<const short8*>(&BlS[wn + i * 16 + l15][quad * 8]);
    }
#pragma unroll
    for (int im = 0; im < 4; im++)
#pragma unroll
      for (int in = 0; in < 4; in++) {
        acc[im][in] = __builtin_amdgcn_mfma_f32_16x16x32_bf16(a_h[im], b_l[in], acc[im][in], 0, 0, 0);
        acc[im][in] = __builtin_amdgcn_mfma_f32_16x16x32_bf16(a_l[im], b_h[in], acc[im][in], 0, 0, 0);
        acc[im][in] = __builtin_amdgcn_mfma_f32_16x16x32_bf16(a_h[im], b_h[in], acc[im][in], 0, 0, 0);
      }
    __syncthreads();
  }

#pragma unroll
  for (int im = 0; im < 4; im++)
#pragma unroll
    for (int in = 0; in < 4; in++)
#pragma unroll
      for (int r = 0; r < 4; r++) {
        const int mr = m0 + wm + im * 16 + quad * 4 + r;
        const int nc = n0 + wn + in * 16 + l15;
        const float val = acc[im][in][r];
        if (fp32out) {
          Cf[(size_t)mr * CD + nc] = val;
        } else {
          short sh, sl;
          split1(val, sh, sl);
          if (sel == 0) {
            O0h[(size_t)mr * CD + nc] = sh; O0l[(size_t)mr * CD + nc] = sl;
          } else if (sel == 1) {
            O1h[(size_t)mr * CD + nc] = sh; O1l[(size_t)mr * CD + nc] = sl;
          } else {  // vT[dim][seq]
            O2h[(size_t)nc * CL + mr] = sh; O2l[(size_t)nc * CL + mr] = sl;
          }
        }
      }
}

// WG = 256 thr (4 waves) x (head h, 8 query rows). LDS = S[8][2048] fp32 (64 KB).
// Phase 1 (NO barriers): waves own disjoint 64-col tiles; 4-term split MFMA;
//   C-frags scattered straight into S (quads 0-1 hold the 8 valid rows).
// Phase 2: wave w owns local rows 2w,2w+1; loads each full row into one f32x32
//   (static 8x ds_read_b128 -> arch VGPRs), register Michelot, writes p back
//   in place as bf16 with a per-row 16B-rotation swizzle.
// Phase 3 (NO barriers): wave w owns dim-block w; P A-frags from swizzled LDS,
//   vT hi/lo B-frags from global, 2-term MFMA per 32-col chunk.
__global__ __launch_bounds__(256, 1) void attn_lds(
    const short* __restrict__ qh, const short* __restrict__ ql,
    const short* __restrict__ kh, const short* __restrict__ kl,
    const short* __restrict__ vhT, const short* __restrict__ vlT,
    short* __restrict__ oh, short* __restrict__ ol) {
  __shared__ float S[8][2048];  // 65536 B == sharedMemPerBlock limit
  char* const Sb = (char*)&S[0][0];
  float* const Sf = &S[0][0];

  const int tid = threadIdx.x, lane = tid & 63, wave = tid >> 6;
  const int l15 = lane & 15, quad = lane >> 4;
  const int bx = blockIdx.x;
  const int qb = (bx & 1) ? (255 - (bx >> 1)) : (bx >> 1);  // heavy+light mix
  const int h = blockIdx.y, q0 = qb * 8, col0 = h * CHD;
  const int nt64 = (q0 + 71) >> 6;          // 64-col tiles covering 0..q0+7

  // ---- Phase 1: scores -> S (scattered C-frag writes, no barriers) ----
  {
    // A-frag rows m: rows q0..q0+7 for m=0..7; m=8..15 duplicate (junk C rows
    // 8..15 are never written). (l15&7) also keeps the q0=2040 block in-bounds.
    const size_t qbase = (size_t)(q0 + (l15 & 7)) * CD + col0 + quad * 8;
    short8 a_h[2], a_l[2];
#pragma unroll
    for (int kb = 0; kb < 2; kb++) {
      a_h[kb] = *reinterpret_cast<const short8*>(qh + qbase + kb * 32);
      a_l[kb] = *reinterpret_cast<const short8*>(ql + qbase + kb * 32);
    }
    for (int jt = wave; jt < nt64; jt += 4) {
      const int j0 = jt * 64;
#pragma unroll
      for (int cb = 0; cb < 4; cb++) {
        const int colb = j0 + cb * 16;
        const size_t kbase = (size_t)(colb + l15) * CD + col0 + quad * 8;
        f32x4 c = {0.f, 0.f, 0.f, 0.f};
#pragma unroll
        for (int kb = 0; kb < 2; kb++) {
          const short8 b_h = *reinterpret_cast<const short8*>(kh + kbase + kb * 32);
          const short8 b_l = *reinterpret_cast<const short8*>(kl + kbase + kb * 32);
          c = __builtin_amdgcn_mfma_f32_16x16x32_bf16(a_l[kb], b_l, c, 0, 0, 0);
          c = __builtin_amdgcn_mfma_f32_16x16x32_bf16(a_h[kb], b_l, c, 0, 0, 0);
          c = __builtin_amdgcn_mfma_f32_16x16x32_bf16(a_l[kb], b_h, c, 0, 0, 0);
          c = __builtin_amdgcn_mfma_f32_16x16x32_bf16(a_h[kb], b_h, c, 0, 0, 0);
        }
        if (quad < 2) {  // C rows quad*4+r = 0..7 are the valid q-rows
#pragma unroll
          for (int r = 0; r < 4; r++)
            S[quad * 4 + r][colb + l15] = c[r] * 0.125f;  // 2^-3: exact
        }
      }
    }
  }
  __syncthreads();

  // ---- Phase 2: per-wave 2-row Michelot in registers ----
  const int ra = 2 * wave, rb = ra + 1;       // local rows
  const int gra = q0 + ra, grb = q0 + rb;     // global rows
  float inva, invb;
  {
    f32x32 sa, sb;  // element 4t+e holds col 4*lane + 256*t + e
#pragma unroll
    for (int t = 0; t < 8; t++) {
      const float4 va = *reinterpret_cast<const float4*>(&S[ra][4 * lane + 256 * t]);
      const float4 vb = *reinterpret_cast<const float4*>(&S[rb][4 * lane + 256 * t]);
      const float ae[4] = {va.x, va.y, va.z, va.w};
      const float be[4] = {vb.x, vb.y, vb.z, vb.w};
#pragma unroll
      for (int e = 0; e < 4; e++) {
        const int col = 4 * lane + 256 * t + e;
        sa[4 * t + e] = (col <= gra) ? ae[e] : NEGS;
        sb[4 * t + e] = (col <= grb) ? be[e] : NEGS;
      }
    }
    entmax2(sa, sb, inva, invb);
    // In-place bf16 P writeback, swizzled: 16B-chunk c16 of local row r goes to
    // slot (c16 + r) & 255. Own-row clobber only; row already fully in regs.
#pragma unroll
    for (int t = 0; t < 8; t++) {
      unsigned long long pka = 0, pkb = 0;
#pragma unroll
      for (int e = 0; e < 4; e++) {
        pka |= (unsigned long long)bf16_bits(sa[4 * t + e]) << (16 * e);
        pkb |= (unsigned long long)bf16_bits(sb[4 * t + e]) << (16 * e);
      }
      const int c16 = (lane >> 1) + 32 * t;   // 8-byte unit u = lane + 64t
      const int half = (lane & 1) * 8;
      *reinterpret_cast<unsigned long long*>(
          Sb + ra * 8192 + (((c16 + ra) & 255) << 4) + half) = pka;
      *reinterpret_cast<unsigned long long*>(
          Sb + rb * 8192 + (((c16 + rb) & 255) << 4) + half) = pkb;
    }
  }
  __syncthreads();

  // ---- Phase 3: P @ V, wave w owns dims 16w..16w+15 (no barriers) ----
  f32x4 acc = {0.f, 0.f, 0.f, 0.f};
  {
    const int nchunk = (q0 + 39) >> 5;        // 32-col chunks covering 0..q0+7
    const int prow = l15 & 7;                 // A rows 8..15 duplicate rows 0..7
    const size_t vrow = (size_t)(col0 + 16 * wave + l15) * CL;
    for (int c = 0; c < nchunk; c++) {
      // A-frag: P[l15][32c + quad*8 .. +7] via the swizzled layout
      const int c16 = 4 * c + quad;
      const short8 pa = *reinterpret_cast<const short8*>(
          Sb + prow * 8192 + (((c16 + prow) & 255) << 4));
      const size_t vb = vrow + 32 * c + quad * 8;
      const short8 vb_h = *reinterpret_cast<const short8*>(vhT + vb);
      const short8 vb_l = *reinterpret_cast<const short8*>(vlT + vb);
      acc = __builtin_amdgcn_mfma_f32_16x16x32_bf16(pa, vb_l, acc, 0, 0, 0);
      acc = __builtin_amdgcn_mfma_f32_16x16x32_bf16(pa, vb_h, acc, 0, 0, 0);
    }
  }

  // ---- inv exchange + epilogue ----
  __syncthreads();                 // P region no longer needed
  if (lane == 0) { Sf[ra] = inva; Sf[rb] = invb; }
  __syncthreads();
  if (quad < 2) {
#pragma unroll
    for (int r = 0; r < 4; r++) {
      const int row = quad * 4 + r;            // local q-row 0..7
      const float o = acc[r] * Sf[row];
      short sh, sl;
      split1(o, sh, sl);
      const size_t oidx = (size_t)(q0 + row) * CD + col0 + 16 * wave + l15;
      oh[oidx] = sh;
      ol[oidx] = sl;
    }
  }
}

extern "C" void kernel_launch(void* const* d_in, const int* in_sizes, int n_in,
                              void* d_out, int out_size, void* d_ws, size_t ws_size,
                              hipStream_t stream) {
  const float* x  = (const float*)d_in[0];
  const float* Wq = (const float*)d_in[1];
  const float* Wk = (const float*)d_in[2];
  const float* Wv = (const float*)d_in[3];
  const float* Wo = (const float*)d_in[4];
  float* out = (float*)d_out;

  // Workspace layout (56 MB total)
  char* ws = (char*)d_ws;
  short* xh  = (short*)(ws + (0ull  << 20));
  short* xl  = (short*)(ws + (4ull  << 20));
  short* wqh = (short*)(ws + (8ull  << 20));
  short* wql = (short*)(ws + (10ull << 20));
  short* wkh = (short*)(ws + (12ull << 20));
  short* wkl = (short*)(ws + (14ull << 20));
  short* wvh = (short*)(ws + (16ull << 20));
  short* wvl = (short*)(ws + (18ull << 20));
  short* woh = (short*)(ws + (20ull << 20));
  short* wol = (short*)(ws + (22ull << 20));
  short* qhp = (short*)(ws + (24ull << 20));
  short* qlp = (short*)(ws + (28ull << 20));
  short* khp = (short*)(ws + (32ull << 20));
  short* klp = (short*)(ws + (36ull << 20));
  short* vhT = (short*)(ws + (40ull << 20));
  short* vlT = (short*)(ws + (44ull << 20));
  short* ohp = (short*)(ws + (48ull << 20));
  short* olp = (short*)(ws + (52ull << 20));

  split_all<<<6144, 256, 0, stream>>>(x, Wq, Wk, Wv, Wo,
                                      xh, xl, wqh, wql, wkh, wkl,
                                      wvh, wvl, woh, wol);

  // Fused QKV: grid.x = 24, sel = x>>3 -> q/k planes row-major, vT transposed
  gemm128_split<<<dim3(24, CL / 128), 256, 0, stream>>>(
      xh, xl, wqh, wql, wkh, wkl, wvh, wvl,
      qhp, qlp, khp, klp, vhT, vlT, nullptr, 0);

  attn_lds<<<dim3(CL / 8, CH), 256, 0, stream>>>(
      qhp, qlp, khp, klp, vhT, vlT, ohp, olp);

  // Wo: grid.x = 8 (sel = 0), fp32 out
  gemm128_split<<<dim3(8, CL / 128), 256, 0, stream>>>(
      ohp, olp, woh, wol, woh, wol, woh, wol,
      ohp, olp, ohp, olp, ohp, olp, out, 1);
}

// Round 9
// 508.996 us; speedup vs baseline: 1.2586x; 1.2586x over previous
//
#include <hip/hip_runtime.h>
#include <hip/hip_bf16.h>

// Problem constants (B=1)
#define CL 2048   // sequence length
#define CD 1024   // hidden
#define CH 16     // heads
#define CHD 64    // head dim
#define NEGS -1e30f

typedef __attribute__((ext_vector_type(8))) short short8;  // 8 x bf16 frag
typedef __attribute__((ext_vector_type(4))) float f32x4;
// One row of scores per WAVE: 32 regs. Small arch footprint + static indices
// everywhere -> compiler keeps it in true VGPRs (R6-R8: multi-row vectors got
// parked in AGPRs, doubling Michelot VALU via v_accvgpr_read round-trips).
typedef __attribute__((ext_vector_type(32))) float f32x32;

__device__ __forceinline__ float wave_sum(float x) {
#pragma unroll
  for (int m = 32; m >= 1; m >>= 1) x += __shfl_xor(x, m, 64);
  return x;
}
__device__ __forceinline__ float wave_max(float x) {
#pragma unroll
  for (int m = 32; m >= 1; m >>= 1) x = fmaxf(x, __shfl_xor(x, m, 64));
  return x;
}

__device__ __forceinline__ void split1(float v, short& h, short& l) {
  __hip_bfloat16 bh = __float2bfloat16(v);
  __hip_bfloat16 bl = __float2bfloat16(v - __bfloat162float(bh));
  h = __builtin_bit_cast(short, bh);
  l = __builtin_bit_cast(short, bl);
}
__device__ __forceinline__ unsigned short bf16_bits(float v) {
  __hip_bfloat16 b = __float2bfloat16(v);
  return (unsigned short)__builtin_bit_cast(short, b);
}

// ---- depth-5 tree helpers over f32x32 ----
__device__ __forceinline__ float tree_sum_valid(const f32x32& s) {
  float t[8];
#pragma unroll
  for (int i = 0; i < 8; i++) {
    const float a = s[i]      > -1e29f ? s[i]      : 0.f;
    const float b = s[i + 8]  > -1e29f ? s[i + 8]  : 0.f;
    const float c = s[i + 16] > -1e29f ? s[i + 16] : 0.f;
    const float d = s[i + 24] > -1e29f ? s[i + 24] : 0.f;
    t[i] = (a + b) + (c + d);
  }
#pragma unroll
  for (int i = 0; i < 4; i++) t[i] += t[i + 4];
  t[0] += t[2]; t[1] += t[3];
  return t[0] + t[1];
}
__device__ __forceinline__ float tree_max(const f32x32& s) {
  float t[8];
#pragma unroll
  for (int i = 0; i < 8; i++)
    t[i] = fmaxf(fmaxf(s[i], s[i + 8]), fmaxf(s[i + 16], s[i + 24]));
#pragma unroll
  for (int i = 0; i < 4; i++) t[i] = fmaxf(t[i], t[i + 4]);
  return fmaxf(fmaxf(t[0], t[2]), fmaxf(t[1], t[3]));
}
__device__ __forceinline__ void masked_sc(const f32x32& s, float tau,
                                          float& cs, float& cn) {
  float ts[8], tc[8];
#pragma unroll
  for (int i = 0; i < 8; i++) {
    const float a = s[i], b = s[i + 8], c = s[i + 16], d = s[i + 24];
    ts[i] = ((a > tau ? a : 0.f) + (b > tau ? b : 0.f)) +
            ((c > tau ? c : 0.f) + (d > tau ? d : 0.f));
    tc[i] = ((a > tau ? 1.f : 0.f) + (b > tau ? 1.f : 0.f)) +
            ((c > tau ? 1.f : 0.f) + (d > tau ? 1.f : 0.f));
  }
#pragma unroll
  for (int i = 0; i < 4; i++) { ts[i] += ts[i + 4]; tc[i] += tc[i + 4]; }
  ts[0] += ts[2]; ts[1] += ts[3]; tc[0] += tc[2]; tc[1] += tc[3];
  cs = ts[0] + ts[1];
  cn = tc[0] + tc[1];
}
__device__ __forceinline__ float relu_store_sum(f32x32& s, float ts_) {
  float t[8];
#pragma unroll
  for (int i = 0; i < 8; i++) {
    float a = s[i] - ts_;      a = a > 0.f ? a : 0.f;
    float b = s[i + 8] - ts_;  b = b > 0.f ? b : 0.f;
    float c = s[i + 16] - ts_; c = c > 0.f ? c : 0.f;
    float d = s[i + 24] - ts_; d = d > 0.f ? d : 0.f;
    s[i] = a; s[i + 8] = b; s[i + 16] = c; s[i + 24] = d;
    t[i] = (a + b) + (c + d);
  }
#pragma unroll
  for (int i = 0; i < 4; i++) t[i] += t[i + 4];
  t[0] += t[2]; t[1] += t[3];
  return t[0] + t[1];
}

// Single-row warm-start Michelot (same arithmetic as the R7/R8 passing
// entmax2, one row). tau* in [max-1, max-1/n] => {s > max-1.000001} is a
// superset of the support; fixpoint count == reference's sort-based
// k_support. Reference quirk kept: tau_star = (FULL masked sum - 1)/cnt.
// Overwrites s with unnormalized p; returns 1/(psum+1e-10).
__device__ __forceinline__ float entmax1(f32x32& s) {
  const float ss = wave_sum(tree_sum_valid(s));
  const float m = wave_max(tree_max(s));
  float tau = m - 1.000001f;
  int cnt = 0;
  for (int it = 0; it < 64; it++) {
    float cs, cn;
    masked_sc(s, tau, cs, cn);
    cs = wave_sum(cs);
    cn = wave_sum(cn);
    const int nc = (int)cn;
    if (nc == cnt) break;   // wave-uniform
    cnt = nc;
    tau = (cs - 1.f) / cn;
  }
  const float ts = (ss - 1.f) / (float)cnt;
  return 1.f / (wave_sum(relu_store_sum(s, ts)) + 1e-10f);
}

// One fused split kernel: fp32 -> bf16 hi/lo planes for x and 4 weights.
__global__ __launch_bounds__(256) void split_all(
    const float* __restrict__ x,  const float* __restrict__ wq,
    const float* __restrict__ wk, const float* __restrict__ wv,
    const float* __restrict__ wo,
    short* __restrict__ xh,  short* __restrict__ xl,
    short* __restrict__ wqh, short* __restrict__ wql,
    short* __restrict__ wkh, short* __restrict__ wkl,
    short* __restrict__ wvh, short* __restrict__ wvl,
    short* __restrict__ woh, short* __restrict__ wol) {
  const int b = blockIdx.x;
  const float* src; short *dh, *dl; int i0;
  if      (b < 2048) { src = x;  dh = xh;  dl = xl;  i0 = b; }
  else if (b < 3072) { src = wq; dh = wqh; dl = wql; i0 = b - 2048; }
  else if (b < 4096) { src = wk; dh = wkh; dl = wkl; i0 = b - 3072; }
  else if (b < 5120) { src = wv; dh = wvh; dl = wvl; i0 = b - 4096; }
  else               { src = wo; dh = woh; dl = wol; i0 = b - 5120; }
  const int i = i0 * 256 + threadIdx.x;
  const float4 v = reinterpret_cast<const float4*>(src)[i];
  const float vv[4] = {v.x, v.y, v.z, v.w};
  short hh[4], ll[4];
#pragma unroll
  for (int e = 0; e < 4; e++) split1(vv[e], hh[e], ll[e]);
  reinterpret_cast<short4*>(dh)[i] = make_short4(hh[0], hh[1], hh[2], hh[3]);
  reinterpret_cast<short4*>(dl)[i] = make_short4(ll[0], ll[1], ll[2], ll[3]);
}

// C[2048,1024] = (Ah+Al) * (B?h+B?l)^T via 3-term split-bf16 MFMA.
// 128x128 tile/WG, LDS-staged BK=32. Epilogue: fp32out -> Cf; else bf16 hi/lo
// planes (sel 2 = vT transposed [dim][seq] for the P@V B-operand).
__global__ __launch_bounds__(256, 2) void gemm128_split(
    const short* __restrict__ Ah, const short* __restrict__ Al,
    const short* __restrict__ B0h, const short* __restrict__ B0l,
    const short* __restrict__ B1h, const short* __restrict__ B1l,
    const short* __restrict__ B2h, const short* __restrict__ B2l,
    short* __restrict__ O0h, short* __restrict__ O0l,
    short* __restrict__ O1h, short* __restrict__ O1l,
    short* __restrict__ O2h, short* __restrict__ O2l,
    float* __restrict__ Cf, int fp32out) {
  __shared__ short AhS[128][32], AlS[128][32], BhS[128][32], BlS[128][32];
  const int tid = threadIdx.x, lane = tid & 63, wave = tid >> 6;
  const int l15 = lane & 15, quad = lane >> 4;
  const int sel = blockIdx.x >> 3, nb = blockIdx.x & 7;
  const short* Bh = sel == 0 ? B0h : (sel == 1 ? B1h : B2h);
  const short* Bl = sel == 0 ? B0l : (sel == 1 ? B1l : B2l);
  const int m0 = blockIdx.y * 128, n0 = nb * 128;
  const int wm = (wave >> 1) * 64, wn = (wave & 1) * 64;

  f32x4 acc[4][4];
#pragma unroll
  for (int i = 0; i < 4; i++)
#pragma unroll
    for (int j = 0; j < 4; j++) acc[i][j] = {0.f, 0.f, 0.f, 0.f};

  const short* gsrc = wave == 0 ? Ah : wave == 1 ? Al : wave == 2 ? Bh : Bl;
  short(*ldst)[32] = wave == 0 ? AhS : wave == 1 ? AlS : wave == 2 ? BhS : BlS;
  const int srow0 = (wave < 2) ? m0 : n0;

  for (int k0 = 0; k0 < CD; k0 += 32) {
#pragma unroll
    for (int i = 0; i < 8; i++) {
      const int ci = i * 64 + lane;
      const int r = ci >> 2, kc = (ci & 3) * 8;
      *reinterpret_cast<short8*>(&ldst[r][kc]) =
          *reinterpret_cast<const short8*>(&gsrc[(size_t)(srow0 + r) * CD + k0 + kc]);
    }
    __syncthreads();
    short8 a_h[4], a_l[4], b_h[4], b_l[4];
#pragma unroll
    for (int i = 0; i < 4; i++) {
      a_h[i] = *reinterpret_cast<const short8*>(&AhS[wm + i * 16 + l15][quad * 8]);
      a_l[i] = *reinterpret_cast<const short8*>(&AlS[wm + i * 16 + l15][quad * 8]);
      b_h[i] = *reinterpret_cast<const short8*>(&BhS[wn + i * 16 + l15][quad * 8]);
      b_l[i] = *reinterpret_cast<const short8*>(&BlS[wn + i * 16 + l15][quad * 8]);
    }
#pragma unroll
    for (int im = 0; im < 4; im++)
#pragma unroll
      for (int in = 0; in < 4; in++) {
        acc[im][in] = __builtin_amdgcn_mfma_f32_16x16x32_bf16(a_h[im], b_l[in], acc[im][in], 0, 0, 0);
        acc[im][in] = __builtin_amdgcn_mfma_f32_16x16x32_bf16(a_l[im], b_h[in], acc[im][in], 0, 0, 0);
        acc[im][in] = __builtin_amdgcn_mfma_f32_16x16x32_bf16(a_h[im], b_h[in], acc[im][in], 0, 0, 0);
      }
    __syncthreads();
  }

#pragma unroll
  for (int im = 0; im < 4; im++)
#pragma unroll
    for (int in = 0; in < 4; in++)
#pragma unroll
      for (int r = 0; r < 4; r++) {
        const int mr = m0 + wm + im * 16 + quad * 4 + r;
        const int nc = n0 + wn + in * 16 + l15;
        const float val = acc[im][in][r];
        if (fp32out) {
          Cf[(size_t)mr * CD + nc] = val;
        } else {
          short sh, sl;
          split1(val, sh, sl);
          if (sel == 0) {
            O0h[(size_t)mr * CD + nc] = sh; O0l[(size_t)mr * CD + nc] = sl;
          } else if (sel == 1) {
            O1h[(size_t)mr * CD + nc] = sh; O1l[(size_t)mr * CD + nc] = sl;
          } else {  // vT[dim][seq]
            O2h[(size_t)nc * CL + mr] = sh; O2l[(size_t)nc * CL + mr] = sl;
          }
        }
      }
}

// WG = 1024 thr (16 waves) x (head h, 16 query rows). Wave w owns row q0+w.
// Phase 1: 256-col tiles; wave w computes col-block 16w..16w+15 via 4-term
//   split MFMA (all 16 C-rows valid); scores gathered so lane ll owns cols
//   {64*tt + ll} of its wave's row -> conflict-free b32 gather, static indices.
// Phase 2: all 16 rows' Michelot run in PARALLEL (one wave each), scores in
//   true VGPRs (32 regs/wave).
// Phase 3: P single-plane bf16 in LDS; wave w = (kgroup w>>2, dim-block w&3);
//   vT hi/lo B-frags from global; one LDS partial-reduce at the end.
__global__ __launch_bounds__(1024, 4) void attn16(
    const short* __restrict__ qh, const short* __restrict__ ql,
    const short* __restrict__ kh, const short* __restrict__ kl,
    const short* __restrict__ vhT, const short* __restrict__ vlT,
    short* __restrict__ oh, short* __restrict__ ol) {
  __shared__ float Stile[16][260];           // 16.6 KB; scatter 2-way, gather 0-way
  __shared__ unsigned short Ptile[16][264];  // 8.25 KB; A-frag reads at b128 floor
  __shared__ float Rtile[4][16][68];         // 17.4 KB partial PV
  __shared__ float invS[16];

  const int tid = threadIdx.x, lane = tid & 63, wave = tid >> 6;
  const int l15 = lane & 15, quad = lane >> 4;
  const int bx = blockIdx.x;
  const int qb = (bx & 1) ? (127 - (bx >> 1)) : (bx >> 1);  // heavy+light mix
  const int h = blockIdx.y, q0 = qb * 16, col0 = h * CHD;
  const int grow = q0 + wave;                 // this wave's global q-row
  const int ntiles = (q0 + 271) >> 8;         // 256-col tiles covering 0..q0+15

  // Q A-frags (rows q0..q0+15): m=l15, k=kb*32+quad*8+j [m89/m91 layout]
  short8 a_h[2], a_l[2];
  {
    const size_t qbase = (size_t)(q0 + l15) * CD + col0 + quad * 8;
#pragma unroll
    for (int kb = 0; kb < 2; kb++) {
      a_h[kb] = *reinterpret_cast<const short8*>(qh + qbase + kb * 32);
      a_l[kb] = *reinterpret_cast<const short8*>(ql + qbase + kb * 32);
    }
  }

  f32x32 s;
#pragma unroll
  for (int t = 0; t < 32; t++) s[t] = NEGS;

  // ---- Phase 1: scores ----
#pragma unroll
  for (int jt = 0; jt < 8; jt++) {
    if (jt < ntiles) {                        // WG-uniform
      const int j0 = jt * 256;
      // B-frags: K rows j0 + 16*wave + l15 (this wave's 16 seq-cols)
      const size_t kbase = (size_t)(j0 + 16 * wave + l15) * CD + col0 + quad * 8;
      f32x4 c = {0.f, 0.f, 0.f, 0.f};
#pragma unroll
      for (int kb = 0; kb < 2; kb++) {
        const short8 b_h = *reinterpret_cast<const short8*>(kh + kbase + kb * 32);
        const short8 b_l = *reinterpret_cast<const short8*>(kl + kbase + kb * 32);
        c = __builtin_amdgcn_mfma_f32_16x16x32_bf16(a_l[kb], b_l, c, 0, 0, 0);
        c = __builtin_amdgcn_mfma_f32_16x16x32_bf16(a_h[kb], b_l, c, 0, 0, 0);
        c = __builtin_amdgcn_mfma_f32_16x16x32_bf16(a_l[kb], b_h, c, 0, 0, 0);
        c = __builtin_amdgcn_mfma_f32_16x16x32_bf16(a_h[kb], b_h, c, 0, 0, 0);
      }
      // C layout: col(seq within tile) = 16*wave + l15, row(q) = quad*4 + r
#pragma unroll
      for (int r = 0; r < 4; r++) Stile[quad * 4 + r][16 * wave + l15] = c[r];
      __syncthreads();
      // Gather MY row: lane ll owns cols j0 + 64*tt + ll (conflict-free b32)
#pragma unroll
      for (int tt = 0; tt < 4; tt++) {
        const int col = j0 + 64 * tt + lane;
        const float v = Stile[wave][64 * tt + lane] * 0.125f;  // 2^-3: exact
        s[jt * 4 + tt] = (col <= grow) ? v : NEGS;
      }
      __syncthreads();
    }
  }

  // ---- Phase 2: entmax, 16 rows fully parallel (one wave each) ----
  const float inv = entmax1(s);
  if (lane == 0) invS[wave] = inv;

  // ---- Phase 3: P @ V (wave = (kgroup, dim-block)) ----
  f32x4 acc = {0.f, 0.f, 0.f, 0.f};
  const int db = wave & 3, kcg = wave >> 2;
#pragma unroll
  for (int jt = 0; jt < 8; jt++) {
    if (jt < ntiles) {
      // write MY row's p for this tile (bf16; zeros where masked)
#pragma unroll
      for (int tt = 0; tt < 4; tt++)
        Ptile[wave][64 * tt + lane] = bf16_bits(s[jt * 4 + tt]);
      __syncthreads();
      const size_t vrowbase =
          (size_t)(col0 + 16 * db + l15) * CL + jt * 256;
#pragma unroll
      for (int t2 = 0; t2 < 2; t2++) {
        const int kc = 2 * kcg + t2;  // this wave's K-chunk of 32
        const short8 pa =
            *reinterpret_cast<const short8*>(&Ptile[l15][kc * 32 + quad * 8]);
        const size_t vb = vrowbase + kc * 32 + quad * 8;
        const short8 vbh = *reinterpret_cast<const short8*>(vhT + vb);
        const short8 vbl = *reinterpret_cast<const short8*>(vlT + vb);
        acc = __builtin_amdgcn_mfma_f32_16x16x32_bf16(pa, vbl, acc, 0, 0, 0);
        acc = __builtin_amdgcn_mfma_f32_16x16x32_bf16(pa, vbh, acc, 0, 0, 0);
      }
      __syncthreads();
    }
  }

  // ---- Cross-wave K-group reduce + epilogue ----
#pragma unroll
  for (int r = 0; r < 4; r++) Rtile[kcg][quad * 4 + r][db * 16 + l15] = acc[r];
  __syncthreads();
  if (wave < 4) {  // wave u handles dim-block u for all 16 rows
#pragma unroll
    for (int r = 0; r < 4; r++) {
      const int row = quad * 4 + r;
      float o = (Rtile[0][row][wave * 16 + l15] + Rtile[1][row][wave * 16 + l15]) +
                (Rtile[2][row][wave * 16 + l15] + Rtile[3][row][wave * 16 + l15]);
      o *= invS[row];
      short sh, sl;
      split1(o, sh, sl);
      const size_t oidx = (size_t)(q0 + row) * CD + col0 + wave * 16 + l15;
      oh[oidx] = sh;
      ol[oidx] = sl;
    }
  }
}

extern "C" void kernel_launch(void* const* d_in, const int* in_sizes, int n_in,
                              void* d_out, int out_size, void* d_ws, size_t ws_size,
                              hipStream_t stream) {
  const float* x  = (const float*)d_in[0];
  const float* Wq = (const float*)d_in[1];
  const float* Wk = (const float*)d_in[2];
  const float* Wv = (const float*)d_in[3];
  const float* Wo = (const float*)d_in[4];
  float* out = (float*)d_out;

  // Workspace layout (56 MB total)
  char* ws = (char*)d_ws;
  short* xh  = (short*)(ws + (0ull  << 20));
  short* xl  = (short*)(ws + (4ull  << 20));
  short* wqh = (short*)(ws + (8ull  << 20));
  short* wql = (short*)(ws + (10ull << 20));
  short* wkh = (short*)(ws + (12ull << 20));
  short* wkl = (short*)(ws + (14ull << 20));
  short* wvh = (short*)(ws + (16ull << 20));
  short* wvl = (short*)(ws + (18ull << 20));
  short* woh = (short*)(ws + (20ull << 20));
  short* wol = (short*)(ws + (22ull << 20));
  short* qhp = (short*)(ws + (24ull << 20));
  short* qlp = (short*)(ws + (28ull << 20));
  short* khp = (short*)(ws + (32ull << 20));
  short* klp = (short*)(ws + (36ull << 20));
  short* vhT = (short*)(ws + (40ull << 20));
  short* vlT = (short*)(ws + (44ull << 20));
  short* ohp = (short*)(ws + (48ull << 20));
  short* olp = (short*)(ws + (52ull << 20));

  split_all<<<6144, 256, 0, stream>>>(x, Wq, Wk, Wv, Wo,
                                      xh, xl, wqh, wql, wkh, wkl,
                                      wvh, wvl, woh, wol);

  // Fused QKV: grid.x = 24, sel = x>>3 -> q/k planes row-major, vT transposed
  gemm128_split<<<dim3(24, CL / 128), 256, 0, stream>>>(
      xh, xl, wqh, wql, wkh, wkl, wvh, wvl,
      qhp, qlp, khp, klp, vhT, vlT, nullptr, 0);

  attn16<<<dim3(CL / 16, CH), 1024, 0, stream>>>(
      qhp, qlp, khp, klp, vhT, vlT, ohp, olp);

  // Wo: grid.x = 8 (sel = 0), fp32 out
  gemm128_split<<<dim3(8, CL / 128), 256, 0, stream>>>(
      ohp, olp, woh, wol, woh, wol, woh, wol,
      ohp, olp, ohp, olp, ohp, olp, out, 1);
}